// Round 16
// baseline (157.201 us; speedup 1.0000x reference)
//
#include <hip/hip_runtime.h>
#include <hip/hip_bf16.h>

// Problem constants
#define Hh 768
#define Ff 384      // H/2
#define Ee 9
#define Rr 10
#define Bb 8
#define Ss 4096
#define Nn_ENT 64
#define Pp 2016     // N*(N-1)/2
#define CH 16       // chunk size for seq prefix
#define NC 256      // S/CH

typedef short bf16x8 __attribute__((ext_vector_type(8)));
typedef float f32x4 __attribute__((ext_vector_type(4)));

// async global->LDS, 16B per lane. LDS dest is wave-uniform base + lane*16.
__device__ __forceinline__ void async_copy16(void* lds, const void* g) {
  auto* l = (__attribute__((address_space(3))) unsigned int*)(lds);
  auto* p = (const __attribute__((address_space(1))) unsigned int*)(g);
  __builtin_amdgcn_global_load_lds(p, l, 16, 0, 0);
}

// ---------------------------------------------------------------------------
// w1 (768x384 f32, k-major) -> Wt (384x768 bf16) via LDS tile transpose
// ---------------------------------------------------------------------------
__global__ __launch_bounds__(256) void transpose_w1(const float* __restrict__ w1,
                                                    unsigned short* __restrict__ wt) {
  __shared__ unsigned short tile[64][65];
  const int bk = blockIdx.x * 64;   // k block (12)
  const int bc = blockIdx.y * 64;   // col block (6)
  const int c = threadIdx.x & 63, kq = threadIdx.x >> 6;
#pragma unroll
  for (int i = 0; i < 16; ++i) {
    int k = kq * 16 + i;
    float v = w1[(size_t)(bk + k) * Ff + bc + c];
    tile[c][k] = __bfloat16_as_ushort(__float2bfloat16(v));
  }
  __syncthreads();
  const int k2 = threadIdx.x & 63, cq = threadIdx.x >> 6;
#pragma unroll
  for (int i = 0; i < 16; ++i) {
    int c2 = cq * 16 + i;
    wt[(size_t)(bc + c2) * Hh + bk + k2] = tile[c2][k2];
  }
}

// ---------------------------------------------------------------------------
// GEMM1+GEMM2+seq_prep fused, COUNTED-VMCNT double-buffer pipeline (T4):
// raw s_barrier (no drain) + s_waitcnt vmcnt(8): the newer stage's 8
// global_load_lds issues stay IN FLIGHT across both barriers; each wave
// waits only its older stage (vmcnt per-wave, in-order retire -> after the
// barrier all waves' older-stage loads are visible). Static named buffers
// (rule #20); sched_barrier(0) fences (rule #18).
// BM=64 x BN=384, BK=64, 512 threads / 8 waves (2m x 4n).
// LDS 2x64KB + params ~15.4KB = 143.4 KB -> 1 block/CU.
// Swizzles (verified conflict-free, R13): A slot^(row&15); B gran^(row&7).
// ---------------------------------------------------------------------------
__global__ __launch_bounds__(512, 2) void gemm1_fused(const float* __restrict__ A,
                                                      const unsigned short* __restrict__ Wt,
                                                      const float* __restrict__ b1,
                                                      const float* __restrict__ w2,
                                                      const float* __restrict__ b2,
                                                      float* __restrict__ elog,
                                                      float* __restrict__ Pc) {
  __shared__ float As0[64 * 64];                   // 16 KB f32
  __shared__ unsigned short Bs0[384 * 64];         // 48 KB bf16
  __shared__ float As1[64 * 64];                   // 16 KB f32
  __shared__ unsigned short Bs1[384 * 64];         // 48 KB bf16
  __shared__ float w2s[Ff * Ee];                   // 13824 B
  __shared__ float b1s[Ff];                        // 1536 B
  __shared__ float b2s[Ee];
  float* red = (float*)&As0[0];                    // epilogue alias (9216 B)

  const int t = threadIdx.x;
  const int wid = t >> 6, lane = t & 63;
  const int wm = wid >> 2, wn = wid & 3;
  const int fr = lane & 15, fq = lane >> 4;
  const int row0 = blockIdx.x * 64;
  const int bb = row0 >> 12;                       // batch index
  const int c0 = (row0 & (Ss - 1)) >> 4;           // first of 4 chunks

  // cache params in LDS
  for (int i = t; i < Ff * Ee; i += 512) w2s[i] = w2[i];
  for (int i = t; i < Ff; i += 512) b1s[i] = b1[i];
  if (t < Ee) b2s[t] = b2[t];

  const int brow0 = (lane >> 3);
  const int bgr = lane & 7;

  f32x4 acc[2][6] = {};
  const int sB = (fr & 7);                         // B row-xor (row&7 == fr&7)

  // 8 gload_lds issues per wave per stage (A:2 + B:6)
#define STAGE(ASB, BSB, ks) do {                                             \
    const int k0s = (ks) * 64;                                               \
    _Pragma("unroll")                                                        \
    for (int i = 0; i < 2; ++i) {                                            \
      const int rl = (wid * 2 + i) * 4 + (lane >> 4);                        \
      const int g = (lane & 15) ^ (rl & 15);                                 \
      async_copy16(&ASB[(wid * 2 + i) * 256],                                \
                   A + (size_t)(row0 + rl) * Hh + k0s + g * 4);              \
    }                                                                        \
    _Pragma("unroll")                                                        \
    for (int j = 0; j < 6; ++j) {                                            \
      const int e = wid * 6 + j;                                             \
      const int rl = e * 8 + brow0;                                          \
      const int g = bgr ^ (rl & 7);                                          \
      async_copy16(&BSB[e * 512],                                            \
                   Wt + (size_t)rl * Hh + k0s + g * 8);                      \
    }                                                                        \
  } while (0)

#define COMPUTE(ASB, BSB, ks) do {                                           \
    const int k0s = (ks) * 64;                                               \
    _Pragma("unroll")                                                        \
    for (int kk = 0; kk < 2; ++kk) {                                         \
      bf16x8 af[2], bfr[6];                                                  \
      _Pragma("unroll")                                                      \
      for (int m = 0; m < 2; ++m) {                                          \
        const int R = wm * 32 + m * 16 + fr;                                 \
        const int G0 = 2 * (kk * 4 + fq);                                    \
        const float* rowp = &ASB[R * 64];                                    \
        float4 v0 = *(const float4*)(rowp + ((G0 ^ fr) * 4));                \
        float4 v1 = *(const float4*)(rowp + (((G0 + 1) ^ fr) * 4));          \
        union { bf16x8 v; __hip_bfloat162 h2[4]; } u;                        \
        u.h2[0] = __float22bfloat162_rn(float2{v0.x, v0.y});                 \
        u.h2[1] = __float22bfloat162_rn(float2{v0.z, v0.w});                 \
        u.h2[2] = __float22bfloat162_rn(float2{v1.x, v1.y});                 \
        u.h2[3] = __float22bfloat162_rn(float2{v1.z, v1.w});                 \
        af[m] = u.v;                                                         \
      }                                                                      \
      const int gB = ((kk * 4 + fq) ^ sB) * 8;                               \
      _Pragma("unroll")                                                      \
      for (int n = 0; n < 6; ++n)                                            \
        bfr[n] = *(const bf16x8*)&BSB[(wn * 96 + n * 16 + fr) * 64 + gB];    \
      _Pragma("unroll")                                                      \
      for (int m = 0; m < 2; ++m)                                            \
        _Pragma("unroll")                                                    \
        for (int n = 0; n < 6; ++n)                                          \
          acc[m][n] = __builtin_amdgcn_mfma_f32_16x16x32_bf16(af[m], bfr[n], acc[m][n], 0, 0, 0); \
    }                                                                        \
    if (t < 256) {                                                           \
      const int cc = t >> 6, kq = lane & 15, rh = lane >> 4;                 \
      float4 s = {0.f, 0.f, 0.f, 0.f};                                       \
      _Pragma("unroll")                                                      \
      for (int q = 0; q < 4; ++q) {                                          \
        const int row = cc * 16 + rh * 4 + q;                                \
        const int slot = kq ^ (rh * 4 + q);                                  \
        float4 v = *(const float4*)&ASB[row * 64 + slot * 4];                \
        s.x += v.x; s.y += v.y; s.z += v.z; s.w += v.w;                      \
      }                                                                      \
      s.x += __shfl_xor(s.x, 16); s.y += __shfl_xor(s.y, 16);                \
      s.z += __shfl_xor(s.z, 16); s.w += __shfl_xor(s.w, 16);                \
      s.x += __shfl_xor(s.x, 32); s.y += __shfl_xor(s.y, 32);                \
      s.z += __shfl_xor(s.z, 32); s.w += __shfl_xor(s.w, 32);                \
      if (rh == 0)                                                           \
        *(float4*)&Pc[((size_t)(bb * NC + c0 + cc)) * Hh + k0s + kq * 4] = s;\
    }                                                                        \
  } while (0)

  // wait own older-stage loads (counted!), then block-wide barrier
#define WAIT_STAGE8() do {                                                   \
    asm volatile("s_waitcnt vmcnt(8)" ::: "memory");                         \
    __builtin_amdgcn_s_barrier();                                            \
    __builtin_amdgcn_sched_barrier(0);                                       \
  } while (0)
#define WAIT_STAGE0() do {                                                   \
    asm volatile("s_waitcnt vmcnt(0)" ::: "memory");                         \
    __builtin_amdgcn_s_barrier();                                            \
    __builtin_amdgcn_sched_barrier(0);                                       \
  } while (0)
  // all waves done reading the buffer (no drain)
#define END_READS() do {                                                     \
    __builtin_amdgcn_sched_barrier(0);                                       \
    __builtin_amdgcn_s_barrier();                                            \
    __builtin_amdgcn_sched_barrier(0);                                       \
  } while (0)

  STAGE(As0, Bs0, 0);
  STAGE(As1, Bs1, 1);

#pragma unroll 1
  for (int ks = 0; ks < Hh / 64; ks += 2) {
    WAIT_STAGE8();                       // stage ks landed (ks+1 still flying)
    COMPUTE(As0, Bs0, ks);
    END_READS();
    if (ks + 2 < Hh / 64) STAGE(As0, Bs0, ks + 2);
    if (ks + 2 < Hh / 64) { WAIT_STAGE8(); } else { WAIT_STAGE0(); }
    COMPUTE(As1, Bs1, ks + 1);
    END_READS();
    if (ks + 3 < Hh / 64) STAGE(As1, Bs1, ks + 3);
  }
#undef STAGE
#undef COMPUTE
#undef WAIT_STAGE8
#undef WAIT_STAGE0
#undef END_READS

  // ---- fused entity-logits epilogue (h in registers) ----
#pragma unroll
  for (int m = 0; m < 2; ++m) {
#pragma unroll
    for (int j = 0; j < 4; ++j) {
      float p[Ee];
#pragma unroll
      for (int e = 0; e < Ee; ++e) p[e] = 0.f;
#pragma unroll
      for (int n = 0; n < 6; ++n) {
        const int col = wn * 96 + n * 16 + fr;
        const float hv = fmaxf(acc[m][n][j] + b1s[col], 0.f);
        const float* wrow = &w2s[col * Ee];
#pragma unroll
        for (int e = 0; e < Ee; ++e) p[e] = fmaf(hv, wrow[e], p[e]);
      }
#pragma unroll
      for (int mask = 1; mask <= 8; mask <<= 1)
#pragma unroll
        for (int e = 0; e < Ee; ++e) p[e] += __shfl_xor(p[e], mask);
      if (fr < Ee) {
        const int row = wm * 32 + m * 16 + fq * 4 + j;
        red[(wn * 64 + row) * Ee + fr] = p[fr];
      }
    }
  }
  __syncthreads();
  for (int idx = t; idx < 64 * Ee; idx += 512) {
    const int row = idx / Ee, e = idx - row * Ee;
    float v = red[(0 * 64 + row) * Ee + e] + red[(1 * 64 + row) * Ee + e]
            + red[(2 * 64 + row) * Ee + e] + red[(3 * 64 + row) * Ee + e] + b2s[e];
    elog[(size_t)(row0 + row) * Ee + e] = v;
  }
}

// ---------------------------------------------------------------------------
// U/V projection, split-K f32: part[ks][uv] += reprs(512x768) @ rw1-half.
// ---------------------------------------------------------------------------
__global__ __launch_bounds__(256) void gemm_uv_splitk(const float* __restrict__ A,
                                                      const float* __restrict__ rw1,
                                                      float* __restrict__ part) {
  const int uv = blockIdx.z & 1, ks = blockIdx.z >> 1;
  const float* Wp = rw1 + (size_t)uv * Hh * Hh + (size_t)ks * 192 * Hh;
  __shared__ float Ast[16][68];
  __shared__ float Wst[16][68];
  const int t = threadIdx.x;
  const int row0 = blockIdx.x * 64, col0 = blockIdx.y * 64;
  const int tm = (t & 15) * 4, tn = (t >> 4) * 4;
  const int lr = t >> 2, lk = (t & 3) * 4;
  const int wk = t >> 4, wc = (t & 15) * 4;
  float acc[4][4] = {};
  const float* Arow = A + (size_t)(row0 + lr) * Hh + ks * 192 + lk;
  for (int k0 = 0; k0 < 192; k0 += 16) {
    float4 av = *(const float4*)(Arow + k0);
    Ast[lk + 0][lr] = av.x; Ast[lk + 1][lr] = av.y;
    Ast[lk + 2][lr] = av.z; Ast[lk + 3][lr] = av.w;
    *(float4*)&Wst[wk][wc] = *(const float4*)(Wp + (size_t)(k0 + wk) * Hh + col0 + wc);
    __syncthreads();
#pragma unroll
    for (int kk = 0; kk < 16; ++kk) {
      const float4 a = *(const float4*)&Ast[kk][tm];
      const float4 b = *(const float4*)&Wst[kk][tn];
      acc[0][0] = fmaf(a.x, b.x, acc[0][0]); acc[0][1] = fmaf(a.x, b.y, acc[0][1]);
      acc[0][2] = fmaf(a.x, b.z, acc[0][2]); acc[0][3] = fmaf(a.x, b.w, acc[0][3]);
      acc[1][0] = fmaf(a.y, b.x, acc[1][0]); acc[1][1] = fmaf(a.y, b.y, acc[1][1]);
      acc[1][2] = fmaf(a.y, b.z, acc[1][2]); acc[1][3] = fmaf(a.y, b.w, acc[1][3]);
      acc[2][0] = fmaf(a.z, b.x, acc[2][0]); acc[2][1] = fmaf(a.z, b.y, acc[2][1]);
      acc[2][2] = fmaf(a.z, b.z, acc[2][2]); acc[2][3] = fmaf(a.z, b.w, acc[2][3]);
      acc[3][0] = fmaf(a.w, b.x, acc[3][0]); acc[3][1] = fmaf(a.w, b.y, acc[3][1]);
      acc[3][2] = fmaf(a.w, b.z, acc[3][2]); acc[3][3] = fmaf(a.w, b.w, acc[3][3]);
    }
    __syncthreads();
  }
  float* out = part + ((size_t)ks * 2 + uv) * (512 * Hh);
#pragma unroll
  for (int i = 0; i < 4; ++i) {
    float4 o; o.x = acc[i][0]; o.y = acc[i][1]; o.z = acc[i][2]; o.w = acc[i][3];
    *(float4*)(out + (size_t)(row0 + tm + i) * Hh + col0 + tn) = o;
  }
}

// UV[i] = sum of 4 K-split partials
__global__ __launch_bounds__(256) void uv_reduce(const float* __restrict__ part,
                                                 float* __restrict__ uv) {
  const int i = blockIdx.x * 256 + threadIdx.x;   // float4 idx, 196608 total
  const float4* p = (const float4*)part;
  float4 a = p[i], b = p[i + 196608], c = p[i + 2 * 196608], d = p[i + 3 * 196608];
  float4 o;
  o.x = (a.x + b.x) + (c.x + d.x);
  o.y = (a.y + b.y) + (c.y + d.y);
  o.z = (a.z + b.z) + (c.z + d.z);
  o.w = (a.w + b.w) + (c.w + d.w);
  ((float4*)uv)[i] = o;
}

// ---------------------------------------------------------------------------
// In-place inclusive scan of Pc along c, per (b,h). Block = (b, 64 h-values).
// ---------------------------------------------------------------------------
__global__ __launch_bounds__(256) void chunk_scan(float* __restrict__ Pc) {
  __shared__ float tile[NC][64];
  const int b = blockIdx.y;
  const int h0 = blockIdx.x * 64;
  float* base = Pc + (size_t)b * NC * Hh + h0;
  const int l = threadIdx.x & 63, g = threadIdx.x >> 6;
#pragma unroll 4
  for (int c = g * 64; c < g * 64 + 64; ++c)
    tile[c][l] = base[(size_t)c * Hh + l];
  __syncthreads();
  float run = 0.f;
#pragma unroll 4
  for (int c = g * 64; c < g * 64 + 64; ++c) {
    run += tile[c][l];
    tile[c][l] = run;
  }
  __syncthreads();
  float off = 0.f;
#pragma unroll
  for (int gg = 0; gg < 3; ++gg)
    if (gg < g) off += tile[gg * 64 + 63][l];
  __syncthreads();
  if (g > 0) {
#pragma unroll 4
    for (int c = g * 64; c < g * 64 + 64; ++c)
      tile[c][l] += off;
  }
  __syncthreads();
#pragma unroll 4
  for (int c = g * 64; c < g * 64 + 64; ++c)
    base[(size_t)c * Hh + l] = tile[c][l];
}

// ---------------------------------------------------------------------------
// entity_reprs: O(1) chunk-range via inclusive prefix + <=30 edge rows.
// ---------------------------------------------------------------------------
__global__ __launch_bounds__(192) void entity_reprs_k(const float* __restrict__ seq,
                                                      const float* __restrict__ Pc,
                                                      const int* __restrict__ spans,
                                                      float* __restrict__ reprs) {
  const int bn = blockIdx.x;
  const int b = bn >> 6;
  const int start = spans[bn * 2], end = spans[bn * 2 + 1];
  const int cnt = max(end - start, 1);
  const float inv = 1.0f / (float)cnt;
  const int cs = (start + CH - 1) >> 4, ce = end >> 4;
  const float* seqb = seq + (size_t)b * Ss * Hh;
  const float4* Pcb = (const float4*)(Pc + (size_t)b * NC * Hh);
  const int t = threadIdx.x;  // 192 x float4 = 768
  float4 acc = {0.f, 0.f, 0.f, 0.f};
  if (cs <= ce) {
    if (cs < ce) {
      float4 hi = Pcb[(size_t)(ce - 1) * 192 + t];
      acc.x += hi.x; acc.y += hi.y; acc.z += hi.z; acc.w += hi.w;
      if (cs > 0) {
        float4 lo = Pcb[(size_t)(cs - 1) * 192 + t];
        acc.x -= lo.x; acc.y -= lo.y; acc.z -= lo.z; acc.w -= lo.w;
      }
    }
    for (int s = start; s < cs * CH; ++s) {
      float4 v = ((const float4*)(seqb + (size_t)s * Hh))[t];
      acc.x += v.x; acc.y += v.y; acc.z += v.z; acc.w += v.w;
    }
    for (int s = ce * CH; s < end; ++s) {
      float4 v = ((const float4*)(seqb + (size_t)s * Hh))[t];
      acc.x += v.x; acc.y += v.y; acc.z += v.z; acc.w += v.w;
    }
  } else {
    for (int s = start; s < end; ++s) {
      float4 v = ((const float4*)(seqb + (size_t)s * Hh))[t];
      acc.x += v.x; acc.y += v.y; acc.z += v.z; acc.w += v.w;
    }
  }
  float4 o; o.x = acc.x * inv; o.y = acc.y * inv; o.z = acc.z * inv; o.w = acc.w * inv;
  ((float4*)(reprs + (size_t)bn * Hh))[t] = o;
}

// ---------------------------------------------------------------------------
// pooled argmax: one block per entity (512 blocks, 4 waves).
// ---------------------------------------------------------------------------
__global__ __launch_bounds__(256) void pooled_argmax(const float* __restrict__ elog,
                                                     const int* __restrict__ spans,
                                                     float* __restrict__ etypes) {
  __shared__ float red[4][Ee];
  const int bn = blockIdx.x;
  const int b = bn >> 6;
  const int start = spans[bn * 2], end = spans[bn * 2 + 1];
  const int t = threadIdx.x, lane = t & 63, w = t >> 6;
  float acc[Ee];
#pragma unroll
  for (int e = 0; e < Ee; ++e) acc[e] = 0.f;
  const float* p = elog + (size_t)b * Ss * Ee;
  for (int s = start + t; s < end; s += 256) {
    const float* q = p + (size_t)s * Ee;
#pragma unroll
    for (int e = 0; e < Ee; ++e) acc[e] += q[e];
  }
#pragma unroll
  for (int off = 32; off; off >>= 1)
#pragma unroll
    for (int e = 0; e < Ee; ++e) acc[e] += __shfl_down(acc[e], off);
  if (lane == 0) {
#pragma unroll
    for (int e = 0; e < Ee; ++e) red[w][e] = acc[e];
  }
  __syncthreads();
  if (t == 0) {
    int best = 0; float bv = -1e30f;
#pragma unroll
    for (int e = 0; e < Ee; ++e) {
      float v = red[0][e] + red[1][e] + red[2][e] + red[3][e];
      if (v > bv) { bv = v; best = e; }
    }
    etypes[bn] = (float)best;
  }
}

// ---------------------------------------------------------------------------
// relations: 4 pairs per wave (16/block, 1008 blocks) — rw2/rb1 LDS staging
// amortized 4x.
// ---------------------------------------------------------------------------
__global__ __launch_bounds__(256) void relations_k(const float* __restrict__ UV,
                                                   const float* __restrict__ rb1,
                                                   const float* __restrict__ rw2,
                                                   const float* __restrict__ rb2,
                                                   float* __restrict__ rlogits,
                                                   float* __restrict__ rtypes) {
  __shared__ float w2l[Hh * 11];   // 33792 B, [k*11 + r]
  __shared__ float b1l[Hh];        //  3072 B
  const int t = threadIdx.x;
  for (int i = t; i < Hh * Rr; i += 256) {
    const int k = i / Rr, r = i - k * Rr;
    w2l[k * 11 + r] = rw2[i];
  }
  for (int i = t; i < Hh; i += 256) b1l[i] = rb1[i];
  __syncthreads();

  const int lane = t & 63;
  const int pbase = blockIdx.x * 16 + (t >> 6) * 4;
#pragma unroll 1
  for (int pi = 0; pi < 4; ++pi) {
    const int p = pbase + pi;
    const int b = p / Pp, pp = p % Pp;
    int i = 0, off = 0;
    while (off + (Nn_ENT - 1 - i) <= pp) { off += Nn_ENT - 1 - i; ++i; }
    const int j = i + 1 + (pp - off);
    const float* u = UV + ((size_t)b * Nn_ENT + i) * Hh;
    const float* v = UV + (size_t)512 * Hh + ((size_t)b * Nn_ENT + j) * Hh;
    float acc[Rr];
#pragma unroll
    for (int r = 0; r < Rr; ++r) acc[r] = 0.f;
    for (int k = lane; k < Hh; k += 64) {
      float x = fmaxf(u[k] + v[k] + b1l[k], 0.f);
      const float* w = &w2l[k * 11];
#pragma unroll
      for (int r = 0; r < Rr; ++r) acc[r] = fmaf(x, w[r], acc[r]);
    }
#pragma unroll
    for (int off2 = 32; off2; off2 >>= 1)
#pragma unroll
      for (int r = 0; r < Rr; ++r) acc[r] += __shfl_down(acc[r], off2);
    if (lane == 0) {
      int best = 0; float bv = acc[0] + rb2[0];
      rlogits[(size_t)p * Rr + 0] = bv;
#pragma unroll
      for (int r = 1; r < Rr; ++r) {
        float val = acc[r] + rb2[r];
        rlogits[(size_t)p * Rr + r] = val;
        if (val > bv) { bv = val; best = r; }
      }
      rtypes[p] = (float)best;
    }
  }
}

// ---------------------------------------------------------------------------
extern "C" void kernel_launch(void* const* d_in, const int* in_sizes, int n_in,
                              void* d_out, int out_size, void* d_ws, size_t ws_size,
                              hipStream_t stream) {
  const float* seq   = (const float*)d_in[0];
  const int*   spans = (const int*)d_in[2];
  const float* w1    = (const float*)d_in[3];
  const float* b1    = (const float*)d_in[4];
  const float* w2    = (const float*)d_in[5];
  const float* b2    = (const float*)d_in[6];
  const float* rw1   = (const float*)d_in[7];
  const float* rb1   = (const float*)d_in[8];
  const float* rw2   = (const float*)d_in[9];
  const float* rb2   = (const float*)d_in[10];

  float* out_elog = (float*)d_out;               // (B,S,E)   294912
  float* out_rlog = out_elog + 294912;           // (B,P,R)   161280
  float* out_repr = out_rlog + 161280;           // (B,N,H)   393216
  float* out_etyp = out_repr + 393216;           // (B,N)     512
  float* out_rtyp = out_etyp + 512;              // (B,P)     16128

  // workspace layout (bytes):
  float*          ws_pc  = (float*)d_ws;                                  //  6291456
  float*          ws_uv  = (float*)((char*)d_ws + 6291456);               //  3145728
  unsigned short* ws_wt  = (unsigned short*)((char*)d_ws + 9437184);      //   589824
  float*          ws_uvp = (float*)((char*)d_ws + 10027008);              // 12582912

  // 0) w1 -> bf16 transposed
  transpose_w1<<<dim3(12, 6), 256, 0, stream>>>(w1, ws_wt);
  // 1) elog = relu(seq @ w1 + b1) @ w2 + b2  AND  Pc chunk sums (fused,
  //    counted-vmcnt pipeline)
  gemm1_fused<<<512, 512, 0, stream>>>(seq, ws_wt, b1, w2, b2, out_elog, ws_pc);
  // 2) prefix scan of chunk sums
  chunk_scan<<<dim3(Hh / 64, Bb), 256, 0, stream>>>(ws_pc);
  // 3) entity_reprs (prefix diff + edge rows)
  entity_reprs_k<<<512, 192, 0, stream>>>(seq, ws_pc, spans, out_repr);
  // 4) U,V = reprs @ rw1 halves: split-K (4) + reduce
  gemm_uv_splitk<<<dim3(8, 12, 8), 256, 0, stream>>>(out_repr, rw1, ws_uvp);
  uv_reduce<<<768, 256, 0, stream>>>(ws_uvp, ws_uv);
  // 5) entity_types via pooled-logits argmax
  pooled_argmax<<<512, 256, 0, stream>>>(out_elog, spans, out_etyp);
  // 6) relation logits + types
  relations_k<<<1008, 256, 0, stream>>>(ws_uv, rb1, rw2, rb2, out_rlog, out_rtyp);
}

// Round 17
// 139.161 us; speedup vs baseline: 1.1296x; 1.1296x over previous
//
#include <hip/hip_runtime.h>
#include <hip/hip_bf16.h>

// Problem constants
#define Hh 768
#define Ff 384      // H/2
#define Ee 9
#define Rr 10
#define Bb 8
#define Ss 4096
#define Nn_ENT 64
#define Pp 2016     // N*(N-1)/2
#define CH 16       // chunk size for seq prefix
#define NC 256      // S/CH

typedef short bf16x8 __attribute__((ext_vector_type(8)));
typedef float f32x4 __attribute__((ext_vector_type(4)));

// async global->LDS, 16B per lane. LDS dest is wave-uniform base + lane*16.
__device__ __forceinline__ void async_copy16(void* lds, const void* g) {
  auto* l = (__attribute__((address_space(3))) unsigned int*)(lds);
  auto* p = (const __attribute__((address_space(1))) unsigned int*)(g);
  __builtin_amdgcn_global_load_lds(p, l, 16, 0, 0);
}

// ---------------------------------------------------------------------------
// w1 (768x384 f32, k-major) -> Wt (384x768 bf16) via LDS tile transpose
// ---------------------------------------------------------------------------
__global__ __launch_bounds__(256) void transpose_w1(const float* __restrict__ w1,
                                                    unsigned short* __restrict__ wt) {
  __shared__ unsigned short tile[64][65];
  const int bk = blockIdx.x * 64;   // k block (12)
  const int bc = blockIdx.y * 64;   // col block (6)
  const int c = threadIdx.x & 63, kq = threadIdx.x >> 6;
#pragma unroll
  for (int i = 0; i < 16; ++i) {
    int k = kq * 16 + i;
    float v = w1[(size_t)(bk + k) * Ff + bc + c];
    tile[c][k] = __bfloat16_as_ushort(__float2bfloat16(v));
  }
  __syncthreads();
  const int k2 = threadIdx.x & 63, cq = threadIdx.x >> 6;
#pragma unroll
  for (int i = 0; i < 16; ++i) {
    int c2 = cq * 16 + i;
    wt[(size_t)(bc + c2) * Hh + bk + k2] = tile[c2][k2];
  }
}

// ---------------------------------------------------------------------------
// GEMM1+GEMM2+seq_prep fused (champion, verified 139.4us total):
//   elog = relu(seq @ w1 + b1) @ w2 + b2   AND   Pc[b][c][h] chunk sums.
// BM=64 x BN=384, BK=64, 512 threads / 8 waves (2m x 4n).
// A staged RAW F32, LDS[row][slot] = global granule slot^(row&15) (full
// 4-bit XOR): MFMA A-read = two independent float4 loads at (G^fr),((G+1)^fr).
// Pc phase: thread (chunk, kq=lane&15, rh=lane>>4) reads granule kq of 4 rows
// at slot kq^(rh*4+q) (conflict-free), shfl-reduce over rh; waves 0-3 only.
// Single-buffer 2-barrier loop. LDS ~81 KB -> 2 blocks/CU.
// ---------------------------------------------------------------------------
__global__ __launch_bounds__(512, 4) void gemm1_fused(const float* __restrict__ A,
                                                      const unsigned short* __restrict__ Wt,
                                                      const float* __restrict__ b1,
                                                      const float* __restrict__ w2,
                                                      const float* __restrict__ b2,
                                                      float* __restrict__ elog,
                                                      float* __restrict__ Pc) {
  __shared__ float As[64 * 64];                    // 16 KB f32
  __shared__ unsigned short Bs[384 * 64];          // 48 KB bf16
  __shared__ float w2s[Ff * Ee];                   // 13824 B
  __shared__ float b1s[Ff];                        // 1536 B
  __shared__ float b2s[Ee];
  float* red = (float*)&Bs[0];                     // epilogue alias (9216 B)

  const int t = threadIdx.x;
  const int wid = t >> 6, lane = t & 63;
  const int wm = wid >> 2, wn = wid & 3;
  const int fr = lane & 15, fq = lane >> 4;
  const int row0 = blockIdx.x * 64;
  const int bb = row0 >> 12;                       // batch index
  const int c0 = (row0 & (Ss - 1)) >> 4;           // first of 4 chunks

  // cache params in LDS
  for (int i = t; i < Ff * Ee; i += 512) w2s[i] = w2[i];
  for (int i = t; i < Ff; i += 512) b1s[i] = b1[i];
  if (t < Ee) b2s[t] = b2[t];

  // --- staging maps ---
  const int brow0 = (lane >> 3);
  const int bgr = lane & 7;

  f32x4 acc[2][6] = {};
  const int sB = (fr & 7);                         // B row-xor (row&7 == fr&7)

#pragma unroll 1
  for (int ks = 0; ks < Hh / 64; ++ks) {
    const int k0 = ks * 64;
    // stage A (f32): 2 issues per wave
#pragma unroll
    for (int i = 0; i < 2; ++i) {
      const int rl = (wid * 2 + i) * 4 + (lane >> 4);
      const int g = (lane & 15) ^ (rl & 15);
      async_copy16(&As[(wid * 2 + i) * 256],
                   A + (size_t)(row0 + rl) * Hh + k0 + g * 4);
    }
    // stage B (bf16): 6 issues per wave
#pragma unroll
    for (int j = 0; j < 6; ++j) {
      const int e = wid * 6 + j;
      const int rl = e * 8 + brow0;
      const int g = bgr ^ (rl & 7);
      async_copy16(&Bs[e * 512],
                   Wt + (size_t)rl * Hh + k0 + g * 8);
    }
    __syncthreads();   // drains gload_lds; tile visible

    // MFMA over BK=64 (2 halves)
#pragma unroll
    for (int kk = 0; kk < 2; ++kk) {
      bf16x8 af[2], bfr[6];
#pragma unroll
      for (int m = 0; m < 2; ++m) {
        const int R = wm * 32 + m * 16 + fr;       // R&15 == fr
        const int G0 = 2 * (kk * 4 + fq);
        const float* rowp = &As[R * 64];
        float4 v0 = *(const float4*)(rowp + ((G0 ^ fr) * 4));
        float4 v1 = *(const float4*)(rowp + (((G0 + 1) ^ fr) * 4));
        union { bf16x8 v; __hip_bfloat162 h2[4]; } u;
        u.h2[0] = __float22bfloat162_rn(float2{v0.x, v0.y});
        u.h2[1] = __float22bfloat162_rn(float2{v0.z, v0.w});
        u.h2[2] = __float22bfloat162_rn(float2{v1.x, v1.y});
        u.h2[3] = __float22bfloat162_rn(float2{v1.z, v1.w});
        af[m] = u.v;
      }
      const int gB = ((kk * 4 + fq) ^ sB) * 8;
#pragma unroll
      for (int n = 0; n < 6; ++n)
        bfr[n] = *(const bf16x8*)&Bs[(wn * 96 + n * 16 + fr) * 64 + gB];
#pragma unroll
      for (int m = 0; m < 2; ++m)
#pragma unroll
        for (int n = 0; n < 6; ++n)
          acc[m][n] = __builtin_amdgcn_mfma_f32_16x16x32_bf16(af[m], bfr[n], acc[m][n], 0, 0, 0);
    }

    // Pc chunk sums for this step's 64 h-columns (waves 0-3 only).
    if (t < 256) {
      const int cc = t >> 6, kq = lane & 15, rh = lane >> 4;
      float4 s = {0.f, 0.f, 0.f, 0.f};
#pragma unroll
      for (int q = 0; q < 4; ++q) {
        const int row = cc * 16 + rh * 4 + q;
        const int slot = kq ^ (rh * 4 + q);        // reads global granule kq
        float4 v = *(const float4*)&As[row * 64 + slot * 4];
        s.x += v.x; s.y += v.y; s.z += v.z; s.w += v.w;
      }
      s.x += __shfl_xor(s.x, 16); s.y += __shfl_xor(s.y, 16);
      s.z += __shfl_xor(s.z, 16); s.w += __shfl_xor(s.w, 16);
      s.x += __shfl_xor(s.x, 32); s.y += __shfl_xor(s.y, 32);
      s.z += __shfl_xor(s.z, 32); s.w += __shfl_xor(s.w, 32);
      if (rh == 0)
        *(float4*)&Pc[((size_t)(bb * NC + c0 + cc)) * Hh + k0 + kq * 4] = s;
    }
    __syncthreads();   // all reads done; safe to restage / alias
  }

  // ---- fused entity-logits epilogue (h in registers) ----
#pragma unroll
  for (int m = 0; m < 2; ++m) {
#pragma unroll
    for (int j = 0; j < 4; ++j) {
      float p[Ee];
#pragma unroll
      for (int e = 0; e < Ee; ++e) p[e] = 0.f;
#pragma unroll
      for (int n = 0; n < 6; ++n) {
        const int col = wn * 96 + n * 16 + fr;
        const float hv = fmaxf(acc[m][n][j] + b1s[col], 0.f);
        const float* wrow = &w2s[col * Ee];
#pragma unroll
        for (int e = 0; e < Ee; ++e) p[e] = fmaf(hv, wrow[e], p[e]);
      }
#pragma unroll
      for (int mask = 1; mask <= 8; mask <<= 1)
#pragma unroll
        for (int e = 0; e < Ee; ++e) p[e] += __shfl_xor(p[e], mask);
      if (fr < Ee) {
        const int row = wm * 32 + m * 16 + fq * 4 + j;
        red[(wn * 64 + row) * Ee + fr] = p[fr];
      }
    }
  }
  __syncthreads();
  for (int idx = t; idx < 64 * Ee; idx += 512) {
    const int row = idx / Ee, e = idx - row * Ee;
    float v = red[(0 * 64 + row) * Ee + e] + red[(1 * 64 + row) * Ee + e]
            + red[(2 * 64 + row) * Ee + e] + red[(3 * 64 + row) * Ee + e] + b2s[e];
    elog[(size_t)(row0 + row) * Ee + e] = v;
  }
}

// ---------------------------------------------------------------------------
// U/V projection, split-K f32: part[ks][uv] += reprs(512x768) @ rw1-half.
// ---------------------------------------------------------------------------
__global__ __launch_bounds__(256) void gemm_uv_splitk(const float* __restrict__ A,
                                                      const float* __restrict__ rw1,
                                                      float* __restrict__ part) {
  const int uv = blockIdx.z & 1, ks = blockIdx.z >> 1;
  const float* Wp = rw1 + (size_t)uv * Hh * Hh + (size_t)ks * 192 * Hh;
  __shared__ float Ast[16][68];
  __shared__ float Wst[16][68];
  const int t = threadIdx.x;
  const int row0 = blockIdx.x * 64, col0 = blockIdx.y * 64;
  const int tm = (t & 15) * 4, tn = (t >> 4) * 4;
  const int lr = t >> 2, lk = (t & 3) * 4;
  const int wk = t >> 4, wc = (t & 15) * 4;
  float acc[4][4] = {};
  const float* Arow = A + (size_t)(row0 + lr) * Hh + ks * 192 + lk;
  for (int k0 = 0; k0 < 192; k0 += 16) {
    float4 av = *(const float4*)(Arow + k0);
    Ast[lk + 0][lr] = av.x; Ast[lk + 1][lr] = av.y;
    Ast[lk + 2][lr] = av.z; Ast[lk + 3][lr] = av.w;
    *(float4*)&Wst[wk][wc] = *(const float4*)(Wp + (size_t)(k0 + wk) * Hh + col0 + wc);
    __syncthreads();
#pragma unroll
    for (int kk = 0; kk < 16; ++kk) {
      const float4 a = *(const float4*)&Ast[kk][tm];
      const float4 b = *(const float4*)&Wst[kk][tn];
      acc[0][0] = fmaf(a.x, b.x, acc[0][0]); acc[0][1] = fmaf(a.x, b.y, acc[0][1]);
      acc[0][2] = fmaf(a.x, b.z, acc[0][2]); acc[0][3] = fmaf(a.x, b.w, acc[0][3]);
      acc[1][0] = fmaf(a.y, b.x, acc[1][0]); acc[1][1] = fmaf(a.y, b.y, acc[1][1]);
      acc[1][2] = fmaf(a.y, b.z, acc[1][2]); acc[1][3] = fmaf(a.y, b.w, acc[1][3]);
      acc[2][0] = fmaf(a.z, b.x, acc[2][0]); acc[2][1] = fmaf(a.z, b.y, acc[2][1]);
      acc[2][2] = fmaf(a.z, b.z, acc[2][2]); acc[2][3] = fmaf(a.z, b.w, acc[2][3]);
      acc[3][0] = fmaf(a.w, b.x, acc[3][0]); acc[3][1] = fmaf(a.w, b.y, acc[3][1]);
      acc[3][2] = fmaf(a.w, b.z, acc[3][2]); acc[3][3] = fmaf(a.w, b.w, acc[3][3]);
    }
    __syncthreads();
  }
  float* out = part + ((size_t)ks * 2 + uv) * (512 * Hh);
#pragma unroll
  for (int i = 0; i < 4; ++i) {
    float4 o; o.x = acc[i][0]; o.y = acc[i][1]; o.z = acc[i][2]; o.w = acc[i][3];
    *(float4*)(out + (size_t)(row0 + tm + i) * Hh + col0 + tn) = o;
  }
}

// UV[i] = sum of 4 K-split partials
__global__ __launch_bounds__(256) void uv_reduce(const float* __restrict__ part,
                                                 float* __restrict__ uv) {
  const int i = blockIdx.x * 256 + threadIdx.x;   // float4 idx, 196608 total
  const float4* p = (const float4*)part;
  float4 a = p[i], b = p[i + 196608], c = p[i + 2 * 196608], d = p[i + 3 * 196608];
  float4 o;
  o.x = (a.x + b.x) + (c.x + d.x);
  o.y = (a.y + b.y) + (c.y + d.y);
  o.z = (a.z + b.z) + (c.z + d.z);
  o.w = (a.w + b.w) + (c.w + d.w);
  ((float4*)uv)[i] = o;
}

// ---------------------------------------------------------------------------
// In-place inclusive scan of Pc along c, per (b,h). Block = (b, 64 h-values).
// ---------------------------------------------------------------------------
__global__ __launch_bounds__(256) void chunk_scan(float* __restrict__ Pc) {
  __shared__ float tile[NC][64];
  const int b = blockIdx.y;
  const int h0 = blockIdx.x * 64;
  float* base = Pc + (size_t)b * NC * Hh + h0;
  const int l = threadIdx.x & 63, g = threadIdx.x >> 6;
#pragma unroll 4
  for (int c = g * 64; c < g * 64 + 64; ++c)
    tile[c][l] = base[(size_t)c * Hh + l];
  __syncthreads();
  float run = 0.f;
#pragma unroll 4
  for (int c = g * 64; c < g * 64 + 64; ++c) {
    run += tile[c][l];
    tile[c][l] = run;
  }
  __syncthreads();
  float off = 0.f;
#pragma unroll
  for (int gg = 0; gg < 3; ++gg)
    if (gg < g) off += tile[gg * 64 + 63][l];
  __syncthreads();
  if (g > 0) {
#pragma unroll 4
    for (int c = g * 64; c < g * 64 + 64; ++c)
      tile[c][l] += off;
  }
  __syncthreads();
#pragma unroll 4
  for (int c = g * 64; c < g * 64 + 64; ++c)
    base[(size_t)c * Hh + l] = tile[c][l];
}

// ---------------------------------------------------------------------------
// entity_reprs: O(1) chunk-range via inclusive prefix + <=30 edge rows.
// ---------------------------------------------------------------------------
__global__ __launch_bounds__(192) void entity_reprs_k(const float* __restrict__ seq,
                                                      const float* __restrict__ Pc,
                                                      const int* __restrict__ spans,
                                                      float* __restrict__ reprs) {
  const int bn = blockIdx.x;
  const int b = bn >> 6;
  const int start = spans[bn * 2], end = spans[bn * 2 + 1];
  const int cnt = max(end - start, 1);
  const float inv = 1.0f / (float)cnt;
  const int cs = (start + CH - 1) >> 4, ce = end >> 4;
  const float* seqb = seq + (size_t)b * Ss * Hh;
  const float4* Pcb = (const float4*)(Pc + (size_t)b * NC * Hh);
  const int t = threadIdx.x;  // 192 x float4 = 768
  float4 acc = {0.f, 0.f, 0.f, 0.f};
  if (cs <= ce) {
    if (cs < ce) {
      float4 hi = Pcb[(size_t)(ce - 1) * 192 + t];
      acc.x += hi.x; acc.y += hi.y; acc.z += hi.z; acc.w += hi.w;
      if (cs > 0) {
        float4 lo = Pcb[(size_t)(cs - 1) * 192 + t];
        acc.x -= lo.x; acc.y -= lo.y; acc.z -= lo.z; acc.w -= lo.w;
      }
    }
    for (int s = start; s < cs * CH; ++s) {
      float4 v = ((const float4*)(seqb + (size_t)s * Hh))[t];
      acc.x += v.x; acc.y += v.y; acc.z += v.z; acc.w += v.w;
    }
    for (int s = ce * CH; s < end; ++s) {
      float4 v = ((const float4*)(seqb + (size_t)s * Hh))[t];
      acc.x += v.x; acc.y += v.y; acc.z += v.z; acc.w += v.w;
    }
  } else {
    for (int s = start; s < end; ++s) {
      float4 v = ((const float4*)(seqb + (size_t)s * Hh))[t];
      acc.x += v.x; acc.y += v.y; acc.z += v.z; acc.w += v.w;
    }
  }
  float4 o; o.x = acc.x * inv; o.y = acc.y * inv; o.z = acc.z * inv; o.w = acc.w * inv;
  ((float4*)(reprs + (size_t)bn * Hh))[t] = o;
}

// ---------------------------------------------------------------------------
// pooled argmax: one block per entity (512 blocks, 4 waves).
// ---------------------------------------------------------------------------
__global__ __launch_bounds__(256) void pooled_argmax(const float* __restrict__ elog,
                                                     const int* __restrict__ spans,
                                                     float* __restrict__ etypes) {
  __shared__ float red[4][Ee];
  const int bn = blockIdx.x;
  const int b = bn >> 6;
  const int start = spans[bn * 2], end = spans[bn * 2 + 1];
  const int t = threadIdx.x, lane = t & 63, w = t >> 6;
  float acc[Ee];
#pragma unroll
  for (int e = 0; e < Ee; ++e) acc[e] = 0.f;
  const float* p = elog + (size_t)b * Ss * Ee;
  for (int s = start + t; s < end; s += 256) {
    const float* q = p + (size_t)s * Ee;
#pragma unroll
    for (int e = 0; e < Ee; ++e) acc[e] += q[e];
  }
#pragma unroll
  for (int off = 32; off; off >>= 1)
#pragma unroll
    for (int e = 0; e < Ee; ++e) acc[e] += __shfl_down(acc[e], off);
  if (lane == 0) {
#pragma unroll
    for (int e = 0; e < Ee; ++e) red[w][e] = acc[e];
  }
  __syncthreads();
  if (t == 0) {
    int best = 0; float bv = -1e30f;
#pragma unroll
    for (int e = 0; e < Ee; ++e) {
      float v = red[0][e] + red[1][e] + red[2][e] + red[3][e];
      if (v > bv) { bv = v; best = e; }
    }
    etypes[bn] = (float)best;
  }
}

// ---------------------------------------------------------------------------
// relations: 4 pairs per wave (16/block, 1008 blocks) — rw2/rb1 LDS staging
// amortized 4x vs one-pair-per-wave (cuts ~137 MB of redundant L2 staging).
// ---------------------------------------------------------------------------
__global__ __launch_bounds__(256) void relations_k(const float* __restrict__ UV,
                                                   const float* __restrict__ rb1,
                                                   const float* __restrict__ rw2,
                                                   const float* __restrict__ rb2,
                                                   float* __restrict__ rlogits,
                                                   float* __restrict__ rtypes) {
  __shared__ float w2l[Hh * 11];   // 33792 B, [k*11 + r]
  __shared__ float b1l[Hh];        //  3072 B
  const int t = threadIdx.x;
  for (int i = t; i < Hh * Rr; i += 256) {
    const int k = i / Rr, r = i - k * Rr;
    w2l[k * 11 + r] = rw2[i];
  }
  for (int i = t; i < Hh; i += 256) b1l[i] = rb1[i];
  __syncthreads();

  const int lane = t & 63;
  const int pbase = blockIdx.x * 16 + (t >> 6) * 4;
#pragma unroll 1
  for (int pi = 0; pi < 4; ++pi) {
    const int p = pbase + pi;
    const int b = p / Pp, pp = p % Pp;
    int i = 0, off = 0;
    while (off + (Nn_ENT - 1 - i) <= pp) { off += Nn_ENT - 1 - i; ++i; }
    const int j = i + 1 + (pp - off);
    const float* u = UV + ((size_t)b * Nn_ENT + i) * Hh;
    const float* v = UV + (size_t)512 * Hh + ((size_t)b * Nn_ENT + j) * Hh;
    float acc[Rr];
#pragma unroll
    for (int r = 0; r < Rr; ++r) acc[r] = 0.f;
    for (int k = lane; k < Hh; k += 64) {
      float x = fmaxf(u[k] + v[k] + b1l[k], 0.f);
      const float* w = &w2l[k * 11];
#pragma unroll
      for (int r = 0; r < Rr; ++r) acc[r] = fmaf(x, w[r], acc[r]);
    }
#pragma unroll
    for (int off2 = 32; off2; off2 >>= 1)
#pragma unroll
      for (int r = 0; r < Rr; ++r) acc[r] += __shfl_down(acc[r], off2);
    if (lane == 0) {
      int best = 0; float bv = acc[0] + rb2[0];
      rlogits[(size_t)p * Rr + 0] = bv;
#pragma unroll
      for (int r = 1; r < Rr; ++r) {
        float val = acc[r] + rb2[r];
        rlogits[(size_t)p * Rr + r] = val;
        if (val > bv) { bv = val; best = r; }
      }
      rtypes[p] = (float)best;
    }
  }
}

// ---------------------------------------------------------------------------
extern "C" void kernel_launch(void* const* d_in, const int* in_sizes, int n_in,
                              void* d_out, int out_size, void* d_ws, size_t ws_size,
                              hipStream_t stream) {
  const float* seq   = (const float*)d_in[0];
  const int*   spans = (const int*)d_in[2];
  const float* w1    = (const float*)d_in[3];
  const float* b1    = (const float*)d_in[4];
  const float* w2    = (const float*)d_in[5];
  const float* b2    = (const float*)d_in[6];
  const float* rw1   = (const float*)d_in[7];
  const float* rb1   = (const float*)d_in[8];
  const float* rw2   = (const float*)d_in[9];
  const float* rb2   = (const float*)d_in[10];

  float* out_elog = (float*)d_out;               // (B,S,E)   294912
  float* out_rlog = out_elog + 294912;           // (B,P,R)   161280
  float* out_repr = out_rlog + 161280;           // (B,N,H)   393216
  float* out_etyp = out_repr + 393216;           // (B,N)     512
  float* out_rtyp = out_etyp + 512;              // (B,P)     16128

  // workspace layout (bytes):
  float*          ws_pc  = (float*)d_ws;                                  //  6291456
  float*          ws_uv  = (float*)((char*)d_ws + 6291456);               //  3145728
  unsigned short* ws_wt  = (unsigned short*)((char*)d_ws + 9437184);      //   589824
  float*          ws_uvp = (float*)((char*)d_ws + 10027008);              // 12582912

  // 0) w1 -> bf16 transposed
  transpose_w1<<<dim3(12, 6), 256, 0, stream>>>(w1, ws_wt);
  // 1) elog = relu(seq @ w1 + b1) @ w2 + b2  AND  Pc chunk sums (fused)
  gemm1_fused<<<512, 512, 0, stream>>>(seq, ws_wt, b1, w2, b2, out_elog, ws_pc);
  // 2) prefix scan of chunk sums
  chunk_scan<<<dim3(Hh / 64, Bb), 256, 0, stream>>>(ws_pc);
  // 3) entity_reprs (prefix diff + edge rows)
  entity_reprs_k<<<512, 192, 0, stream>>>(seq, ws_pc, spans, out_repr);
  // 4) U,V = reprs @ rw1 halves: split-K (4) + reduce
  gemm_uv_splitk<<<dim3(8, 12, 8), 256, 0, stream>>>(out_repr, rw1, ws_uvp);
  uv_reduce<<<768, 256, 0, stream>>>(ws_uvp, ws_uv);
  // 5) entity_types via pooled-logits argmax
  pooled_argmax<<<512, 256, 0, stream>>>(out_elog, spans, out_etyp);
  // 6) relation logits + types
  relations_k<<<1008, 256, 0, stream>>>(ws_uv, rb1, rw2, rb2, out_rlog, out_rtyp);
}